// Round 1
// baseline (172.670 us; speedup 1.0000x reference)
//
#include <hip/hip_runtime.h>

// Causal flash attention, B=4 L=S=2048 H=8 E=D=64, fp32 in/out, bf16 MFMA.
// Round 8: full restructure.
//  - Pre-pass converts K -> bf16 [B,H,S,E] and V -> bf16 V^T [B,H,D,S] in d_ws
//    (one-time; kills the x17 redundant fp32->bf16 VALU + halves K/V bytes).
//  - Main kernel: NO LDS, NO barriers. 32x32x16 MFMA, 32 q-rows per wave,
//    K/V fragments loaded directly from L1/L2 (per-head working set 512 KB).
//  - S^T = K*Q^T and O^T = V^T*P: col = lane&31 = q for both, so softmax
//    stats / alpha-rescale / 1/l are all in-lane (zero shfl broadcasts).
//  - P (f32, in-lane) -> PV B-operand bf16 frags via pack2 + v_permlane32_swap
//    (T12): one swap fills two frag words for both lane halves.
//  - Wave w of block j handles q-strip {j, 63-j}: every block is exactly 33
//    tile-iters -> perfect causal load balance. h = bx&7 pins heads to XCDs;
//    all 4 blocks/CU share (b,h) -> K/V tiles L1-resident.
// Layouts (guide-verified): A[m=lane&31][k=(lane>>5)*8+j],
// B[k=(lane>>5)*8+j][n=lane&31], C[n=lane&31][m=(reg&3)+8*(reg>>2)+4*(lane>>5)].

typedef unsigned short u16;
typedef unsigned int   u32;
typedef short short8   __attribute__((ext_vector_type(8)));
typedef float floatx16 __attribute__((ext_vector_type(16)));
typedef u32 u32x4      __attribute__((ext_vector_type(4)));

#define B_ 4
#define L_ 2048
#define S_ 2048
#define H_ 8
#define E_ 64
#define D_ 64

// round-half-up fp32->bf16 pair, lo in low 16 bits
static __device__ __forceinline__ u32 pack2(float lo, float hi) {
    const u32 a = __float_as_uint(lo) + 0x8000u;
    const u32 b = __float_as_uint(hi) + 0x8000u;
    return __builtin_amdgcn_perm(b, a, 0x07060302u);
}
static __device__ __forceinline__ u16 bf16c(float x) {
    return (u16)((__float_as_uint(x) + 0x8000u) >> 16);
}
// swap: a.hi32lanes <-> b.lo32lanes  (v_permlane32_swap_b32)
static __device__ __forceinline__ void pl32swap(u32& a, u32& b) {
    asm("v_permlane32_swap_b32 %0, %1" : "+v"(a), "+v"(b));
}
static __device__ __forceinline__ floatx16 zero16() {
    floatx16 z;
    #pragma unroll
    for (int i = 0; i < 16; i++) z[i] = 0.f;
    return z;
}

// ---------------- pre-pass: K depitch + V transpose, fp32 -> bf16 ----------------
__global__ __launch_bounds__(256)
void cvt_kernel(const float* __restrict__ k, const float* __restrict__ v,
                u16* __restrict__ kc, u16* __restrict__ vt)
{
    __shared__ u16 Lt[64 * 72];
    const int bx = blockIdx.x, t = threadIdx.x;
    if (bx < 2048) {
        // K: [B,S,H,E] f32 -> Kc [B,H,S,E] bf16, 8 elems/thread
        const size_t f = ((size_t)bx * 256 + t) * 8;
        const int e0 = (int)(f & 63);
        const int h  = (int)((f >> 6) & 7);
        const int s  = (int)((f >> 9) & 2047);
        const int b  = (int)(f >> 20);
        const float4* kp = (const float4*)(k + f);
        const float4 a0 = kp[0], a1 = kp[1];
        const u32x4 wv = {pack2(a0.x, a0.y), pack2(a0.z, a0.w),
                          pack2(a1.x, a1.y), pack2(a1.z, a1.w)};
        *(u32x4*)&kc[((size_t)(b * 8 + h) * 2048 + s) * 64 + e0] = wv;
    } else {
        // V: [B,S,H,D] f32 -> Vt [B,H,D,S] bf16, 64x64 LDS tile transpose
        const int vb = bx - 2048;
        const int st = vb & 31, h = (vb >> 5) & 7, b = vb >> 8;
        const int s0 = st * 64;
        {
            const int i  = t >> 2;
            const int d0 = (t & 3) * 16;
            const float4* vp = (const float4*)(v + (((size_t)(b * 2048 + s0 + i)) * 8 + h) * 64 + d0);
            const float4 a0 = vp[0], a1 = vp[1], a2 = vp[2], a3 = vp[3];
            const float va[16] = {a0.x,a0.y,a0.z,a0.w, a1.x,a1.y,a1.z,a1.w,
                                  a2.x,a2.y,a2.z,a2.w, a3.x,a3.y,a3.z,a3.w};
            #pragma unroll
            for (int jj = 0; jj < 16; jj++) Lt[(d0 + jj) * 72 + i] = bf16c(va[jj]);
        }
        __syncthreads();
        {
            const int d  = t >> 2;
            const int i0 = (t & 3) * 16;
            const u32x4 w0 = *(const u32x4*)&Lt[d * 72 + i0];
            const u32x4 w1 = *(const u32x4*)&Lt[d * 72 + i0 + 8];
            u16* dst = &vt[(((size_t)(b * 8 + h)) * 64 + d) * 2048 + s0 + i0];
            *(u32x4*)dst = w0;
            *(u32x4*)&dst[8] = w1;
        }
    }
}

// ---------------- main kernel: LDS-free, barrier-free ----------------
// SRC=0: bf16 workspace (fast). SRC=1: direct fp32 fallback (ws too small).
template<int SRC>
__global__ __launch_bounds__(128, 2)
void fa_causal32_kernel(const float* __restrict__ q, const float* __restrict__ kk,
                        const float* __restrict__ vv, const u16* __restrict__ kc,
                        const u16* __restrict__ vt, float* __restrict__ out)
{
    const int tid  = threadIdx.x;
    const int w    = tid >> 6;
    const int lane = tid & 63;
    const int l31  = lane & 31;
    const int hi   = lane >> 5;

    const int bx = blockIdx.x;
    const int h  = bx & 7;               // XCD-resident head
    const int b  = (bx >> 3) & 3;
    const int j  = bx >> 5;              // 0..31
    const int s32 = w ? (63 - j) : j;    // folded strips: block work == 33 tiles
    const int q0  = s32 * 32;
    const int kt_last = s32 >> 1;

    const float kscale = 0.18033688011112042f; // (1/sqrt(64)) * log2(e)

    // ---- Q frags (B-operand of S^T = K*Q^T), kscale folded ----
    const float* qptr = q + (((size_t)b * L_ + q0 + l31) * H_ + h) * E_ + hi * 8;
    short8 qf[4];
    #pragma unroll
    for (int ks = 0; ks < 4; ks++) {
        const float4 a0 = *(const float4*)(qptr + ks * 16);
        const float4 a1 = *(const float4*)(qptr + ks * 16 + 4);
        const u32x4 u = {pack2(a0.x * kscale, a0.y * kscale), pack2(a0.z * kscale, a0.w * kscale),
                         pack2(a1.x * kscale, a1.y * kscale), pack2(a1.z * kscale, a1.w * kscale)};
        qf[ks] = __builtin_bit_cast(short8, u);
    }

    const size_t bh = (size_t)(b * 8 + h);
    const u16* kcb = kc + bh * 2048 * 64;
    const u16* vtb = vt + bh * 64 * 2048;

    // A-operand K frag: K[key = kt*64+mt*32+l31][e = ks*16+hi*8 ..+7]
    auto loadK = [&](int kt, int mt, int ks) -> short8 {
        if constexpr (SRC == 0) {
            const u32x4 u = *(const u32x4*)&kcb[((size_t)(kt * 64 + mt * 32 + l31)) * 64 + ks * 16 + hi * 8];
            return __builtin_bit_cast(short8, u);
        } else {
            const float* p = kk + (((size_t)b * S_ + kt * 64 + mt * 32 + l31) * H_ + h) * E_ + ks * 16 + hi * 8;
            const float4 a0 = *(const float4*)p;
            const float4 a1 = *(const float4*)(p + 4);
            const u32x4 u = {pack2(a0.x, a0.y), pack2(a0.z, a0.w), pack2(a1.x, a1.y), pack2(a1.z, a1.w)};
            return __builtin_bit_cast(short8, u);
        }
    };
    // A-operand V^T frag: V^T[d = nt*32+l31][s = kt*64+ks*16+hi*8 ..+7]
    auto loadV = [&](int kt, int nt, int ks) -> short8 {
        if constexpr (SRC == 0) {
            const u32x4 u = *(const u32x4*)&vtb[((size_t)(nt * 32 + l31)) * 2048 + kt * 64 + ks * 16 + hi * 8];
            return __builtin_bit_cast(short8, u);
        } else {
            float f[8];
            #pragma unroll
            for (int jj = 0; jj < 8; jj++)
                f[jj] = vv[(((size_t)b * S_ + kt * 64 + ks * 16 + hi * 8 + jj) * H_ + h) * D_ + nt * 32 + l31];
            const u32x4 u = {pack2(f[0], f[1]), pack2(f[2], f[3]), pack2(f[4], f[5]), pack2(f[6], f[7])};
            return __builtin_bit_cast(short8, u);
        }
    };

    floatx16 occ[2] = {zero16(), zero16()};  // O^T: [d-tile][reg], col = q = l31
    float m_run = -1e30f, l_run = 0.f;       // in-lane: lane owns q-row q0+l31

    short8 kf[2][4], vf[2][4];
    #pragma unroll
    for (int mt = 0; mt < 2; mt++)
        #pragma unroll
        for (int ks = 0; ks < 4; ks++) { kf[mt][ks] = loadK(0, mt, ks); vf[mt][ks] = loadV(0, mt, ks); }

    for (int kt = 0; kt <= kt_last; kt++) {
        // ---- S^T = K*Q^T : sac[mt], rows = keys (pattern), col = q = l31 ----
        floatx16 sac[2];
        __builtin_amdgcn_s_setprio(1);
        #pragma unroll
        for (int mt = 0; mt < 2; mt++) {
            floatx16 c = zero16();
            #pragma unroll
            for (int ks = 0; ks < 4; ks++)
                c = __builtin_amdgcn_mfma_f32_32x32x16_bf16(kf[mt][ks], qf[ks], c, 0, 0, 0);
            sac[mt] = c;
        }
        __builtin_amdgcn_s_setprio(0);

        // prefetch next K tile (latency hidden under softmax+PV)
        if (kt < kt_last) {
            #pragma unroll
            for (int mt = 0; mt < 2; mt++)
                #pragma unroll
                for (int ks = 0; ks < 4; ks++) kf[mt][ks] = loadK(kt + 1, mt, ks);
        }

        // ---- causal mask (diagonal tile only; wave-uniform branch) ----
        if (kt == kt_last) {
            const int qg = q0 + l31;
            #pragma unroll
            for (int mt = 0; mt < 2; mt++)
                #pragma unroll
                for (int r = 0; r < 16; r++) {
                    const int keyg = kt * 64 + mt * 32 + (r & 3) + (r >> 2) * 8 + hi * 4;
                    if (keyg > qg) sac[mt][r] = -1e30f;
                }
        }

        // ---- online softmax, fully in-lane (32 scores) + 1 shfl_xor(32) ----
        float red[16];
        #pragma unroll
        for (int r = 0; r < 16; r++) red[r] = fmaxf(sac[0][r], sac[1][r]);
        #pragma unroll
        for (int stp = 8; stp > 0; stp >>= 1)
            #pragma unroll
            for (int r = 0; r < stp; r++) red[r] = fmaxf(red[r], red[r + stp]);
        const float mx   = fmaxf(red[0], __shfl_xor(red[0], 32));
        const float mnew = fmaxf(m_run, mx);
        const float alpha = exp2f(m_run - mnew);
        m_run = mnew;

        float sum[16];
        #pragma unroll
        for (int r = 0; r < 16; r++) {
            sac[0][r] = exp2f(sac[0][r] - mnew);
            sac[1][r] = exp2f(sac[1][r] - mnew);
            sum[r] = sac[0][r] + sac[1][r];
        }
        #pragma unroll
        for (int stp = 8; stp > 0; stp >>= 1)
            #pragma unroll
            for (int r = 0; r < stp; r++) sum[r] += sum[r + stp];
        const float ps = sum[0] + __shfl_xor(sum[0], 32);
        l_run = l_run * alpha + ps;

        // in-lane O rescale (col = q = l31 owns alpha)
        #pragma unroll
        for (int nt = 0; nt < 2; nt++)
            #pragma unroll
            for (int r = 0; r < 16; r++) occ[nt][r] *= alpha;

        // ---- P -> bf16 pairs: pk[mt][r2*2+half] = keys 32mt+8r2+4hi+{2half,2half+1} ----
        u32 pk0[8], pk1[8];
        #pragma unroll
        for (int r2 = 0; r2 < 4; r2++) {
            pk0[r2 * 2 + 0] = pack2(sac[0][4 * r2 + 0], sac[0][4 * r2 + 1]);
            pk0[r2 * 2 + 1] = pack2(sac[0][4 * r2 + 2], sac[0][4 * r2 + 3]);
            pk1[r2 * 2 + 0] = pack2(sac[1][4 * r2 + 0], sac[1][4 * r2 + 1]);
            pk1[r2 * 2 + 1] = pack2(sac[1][4 * r2 + 2], sac[1][4 * r2 + 3]);
        }

        // ---- O^T += V^T * P : per ks, 2 permlane32_swaps build the B-frag ----
        __builtin_amdgcn_s_setprio(1);
        #pragma unroll
        for (int ks = 0; ks < 4; ks++) {
            const int u = (ks & 1) * 4;   // A-block r2=2(ks&1), B-block r2+1; mt = ks>>1
            u32 w0, w1, w2, w3;
            if (ks < 2) { w0 = pk0[u]; w1 = pk0[u + 1]; w2 = pk0[u + 2]; w3 = pk0[u + 3]; }
            else        { w0 = pk1[u]; w1 = pk1[u + 1]; w2 = pk1[u + 2]; w3 = pk1[u + 3]; }
            pl32swap(w0, w2);   // -> frag words k=8hi+{0,1} and {4,5}
            pl32swap(w1, w3);   // -> frag words k=8hi+{2,3} and {6,7}
            const u32x4 pw = {w0, w1, w2, w3};
            const short8 pf = __builtin_bit_cast(short8, pw);
            occ[0] = __builtin_amdgcn_mfma_f32_32x32x16_bf16(vf[0][ks], pf, occ[0], 0, 0, 0);
            occ[1] = __builtin_amdgcn_mfma_f32_32x32x16_bf16(vf[1][ks], pf, occ[1], 0, 0, 0);
        }
        __builtin_amdgcn_s_setprio(0);

        // prefetch next V tile
        if (kt < kt_last) {
            #pragma unroll
            for (int nt = 0; nt < 2; nt++)
                #pragma unroll
                for (int ks = 0; ks < 4; ks++) vf[nt][ks] = loadV(kt + 1, nt, ks);
        }
    }

    // ---- epilogue: O = O^T / l, in-lane; d = nt*32 + 8*r2 + 4*hi + (0..3) ----
    const float inv = 1.0f / l_run;
    float* op = out + (((size_t)b * L_ + q0 + l31) * H_ + h) * D_;
    #pragma unroll
    for (int nt = 0; nt < 2; nt++)
        #pragma unroll
        for (int r2 = 0; r2 < 4; r2++) {
            const float4 o = {occ[nt][4 * r2 + 0] * inv, occ[nt][4 * r2 + 1] * inv,
                              occ[nt][4 * r2 + 2] * inv, occ[nt][4 * r2 + 3] * inv};
            *(float4*)(op + nt * 32 + r2 * 8 + hi * 4) = o;
        }
}

extern "C" void kernel_launch(void* const* d_in, const int* in_sizes, int n_in,
                              void* d_out, int out_size, void* d_ws, size_t ws_size,
                              hipStream_t stream) {
    const float* q = (const float*)d_in[0];
    const float* k = (const float*)d_in[1];
    const float* v = (const float*)d_in[2];
    // d_in[3] = attn_mask: fixed causal triu -> handled analytically in-kernel.
    float* out = (float*)d_out;

    const size_t elems = (size_t)B_ * H_ * S_ * E_;   // per tensor
    const size_t need  = elems * 2 * 2;               // Kc + Vt, bf16
    if (d_ws != nullptr && ws_size >= need) {
        u16* kc = (u16*)d_ws;
        u16* vt = kc + elems;
        cvt_kernel<<<dim3(3072), dim3(256), 0, stream>>>(k, v, kc, vt);
        fa_causal32_kernel<0><<<dim3(1024), dim3(128), 0, stream>>>(q, k, v, kc, vt, out);
    } else {
        fa_causal32_kernel<1><<<dim3(1024), dim3(128), 0, stream>>>(q, k, v, nullptr, nullptr, out);
    }
}

// Round 2
// 153.418 us; speedup vs baseline: 1.1255x; 1.1255x over previous
//
#include <hip/hip_runtime.h>

// Causal flash attention, B=4 L=S=2048 H=8 E=D=64, fp32 in/out, bf16 MFMA.
// Round 9: (1) FRAG-MAJOR workspace layout -- each 32x32x16 MFMA A-fragment is
// stored as a contiguous 1KB block (lane-linear), so every K/V frag load is a
// coalesced 8-line burst instead of a 32-line gather (round-8 profile: ~70% of
// cycles were L1 line serialization). (2) SPLIT-K for long strips: strips
// s32>=32 are processed by 2 waves over disjoint K-halves, merged via LDS at
// block end -- cuts the critical chain 32 -> 16 tiles and lifts the ~52%
// concurrency loss (Occ 14% vs 25%) from all-resident unbalanced waves.
// (3) defer-max (T13, THR=8 in log2 domain) skips the O-rescale pass on most
// tiles. Math/P-layout identical to round 8 (hardware-validated).

typedef unsigned short u16;
typedef unsigned int   u32;
typedef short short8   __attribute__((ext_vector_type(8)));
typedef float floatx16 __attribute__((ext_vector_type(16)));
typedef u32 u32x4      __attribute__((ext_vector_type(4)));

#define B_ 4
#define L_ 2048
#define S_ 2048
#define H_ 8
#define E_ 64
#define D_ 64

// round-half-up fp32->bf16 pair, lo in low 16 bits
static __device__ __forceinline__ u32 pack2(float lo, float hi) {
    const u32 a = __float_as_uint(lo) + 0x8000u;
    const u32 b = __float_as_uint(hi) + 0x8000u;
    return __builtin_amdgcn_perm(b, a, 0x07060302u);
}
static __device__ __forceinline__ u16 bf16c(float x) {
    return (u16)((__float_as_uint(x) + 0x8000u) >> 16);
}
// v_permlane32_swap_b32: a.hi32lanes <-> b.lo32lanes
static __device__ __forceinline__ void pl32swap(u32& a, u32& b) {
    asm("v_permlane32_swap_b32 %0, %1" : "+v"(a), "+v"(b));
}
static __device__ __forceinline__ floatx16 zero16() {
    floatx16 z;
    #pragma unroll
    for (int i = 0; i < 16; i++) z[i] = 0.f;
    return z;
}

// ---------------- pre-pass: fp32 -> bf16, FRAG-MAJOR tiles ----------------
// Kc tile (per bh,kt; 4096 u16): [F=mt*4+ks][lane=hi*32+l31][j]
//   holds K[b][s=kt*64+mt*32+l31][h][e=ks*16+hi*8+j]
// Vt tile (per bh,kt; 4096 u16): [F=nt*4+ks][lane=hi*32+l31][j]
//   holds V[b][s=kt*64+ks*16+hi*8+j][h][d=nt*32+l31]
__global__ __launch_bounds__(256)
void cvt_kernel(const float* __restrict__ k, const float* __restrict__ v,
                u16* __restrict__ kc, u16* __restrict__ vt)
{
    __shared__ u16 Lt[64 * 72];
    const int bx = blockIdx.x, t = threadIdx.x;
    const int tile = bx & 1023;
    const int kt = tile & 31, h = (tile >> 5) & 7, b = tile >> 8;
    const int F  = t >> 5;
    const int hi = (t >> 4) & 1;
    const int l0 = (t & 15) * 2;

    if (bx < 1024) {
        // K: rows s, s+1 ; e-chunk (ks,hi). Writes are thread-linear (32B/thr).
        const int mt = F >> 2, ks = F & 3;
        const int s  = kt * 64 + mt * 32 + l0;
        const int e  = ks * 16 + hi * 8;
        const float* p0 = k + (((size_t)(b * S_ + s)) * H_ + h) * E_ + e;
        const float4 a0 = ((const float4*)p0)[0], a1 = ((const float4*)p0)[1];
        const float* p1 = p0 + H_ * E_;
        const float4 b0 = ((const float4*)p1)[0], b1 = ((const float4*)p1)[1];
        u16* dst = kc + ((size_t)(b * 8 + h)) * 131072 + (size_t)kt * 4096 + t * 16;
        *(u32x4*)dst = (u32x4){pack2(a0.x, a0.y), pack2(a0.z, a0.w),
                               pack2(a1.x, a1.y), pack2(a1.z, a1.w)};
        *(u32x4*)(dst + 8) = (u32x4){pack2(b0.x, b0.y), pack2(b0.z, b0.w),
                                     pack2(b1.x, b1.y), pack2(b1.z, b1.w)};
    } else {
        // V: 64x64 LDS transpose, then thread-linear frag-major writes.
        {
            const int i  = t >> 2;
            const int d0 = (t & 3) * 16;
            const float* vp = v + (((size_t)(b * S_ + kt * 64 + i)) * H_ + h) * D_ + d0;
            const float4 a0 = ((const float4*)vp)[0], a1 = ((const float4*)vp)[1];
            const float4 a2 = ((const float4*)vp)[2], a3 = ((const float4*)vp)[3];
            const float va[16] = {a0.x,a0.y,a0.z,a0.w, a1.x,a1.y,a1.z,a1.w,
                                  a2.x,a2.y,a2.z,a2.w, a3.x,a3.y,a3.z,a3.w};
            #pragma unroll
            for (int jj = 0; jj < 16; jj++) Lt[(d0 + jj) * 72 + i] = bf16c(va[jj]);
        }
        __syncthreads();
        {
            const int nt = F >> 2, ks = F & 3;
            const int d1 = nt * 32 + l0;
            u16* dst = vt + ((size_t)(b * 8 + h)) * 131072 + (size_t)kt * 4096 + t * 16;
            *(u32x4*)dst       = *(const u32x4*)&Lt[(d1    ) * 72 + ks * 16 + hi * 8];
            *(u32x4*)(dst + 8) = *(const u32x4*)&Lt[(d1 + 1) * 72 + ks * 16 + hi * 8];
        }
    }
}

// ---------------- main kernel ----------------
// Grid 1536 x 128thr (2 waves). bx<1024: SPLIT block -- both waves on strip
// s32=63-(bx>>5), wave0 K-tiles [0,mid), wave1 [mid,klast] (+diag mask), LDS
// merge at end. bx>=1024: PAIRED block -- wave w on strip (w? jj : 31-jj),
// independent full K-range, direct output. All block durations 9..17 tiles.
template<int SRC>
__global__ __launch_bounds__(128, 2)
void fa_kernel(const float* __restrict__ q, const float* __restrict__ kk,
               const float* __restrict__ vv, const u16* __restrict__ kc,
               const u16* __restrict__ vt, float* __restrict__ out)
{
    __shared__ float Ls[64 * 33 + 128];   // partial O (padded) + m + l

    const int tid  = threadIdx.x;
    const int w    = tid >> 6;
    const int lane = tid & 63;
    const int l31  = lane & 31;
    const int hi   = lane >> 5;

    const int bx = blockIdx.x;
    int h, b, s32, kt0, ktend;
    bool split, diag;
    if (bx < 1024) {
        split = true;
        h = bx & 7; b = (bx >> 3) & 3;
        s32 = 63 - (bx >> 5);
        const int klast = s32 >> 1;
        const int mid   = (klast + 1) >> 1;
        if (w == 0) { kt0 = 0;   ktend = mid - 1; diag = false; }
        else        { kt0 = mid; ktend = klast;   diag = true;  }
    } else {
        split = false; diag = true;
        const int idx = bx - 1024;
        h = idx & 7; b = (idx >> 3) & 3;
        const int jj = idx >> 5;
        s32 = w ? jj : (31 - jj);
        kt0 = 0; ktend = s32 >> 1;
    }
    const int q0 = s32 * 32;

    const float kscale = 0.18033688011112042f; // (1/sqrt(64)) * log2(e)

    // ---- Q frags (B-operand of S^T = K*Q^T), kscale folded ----
    const float* qptr = q + (((size_t)b * L_ + q0 + l31) * H_ + h) * E_ + hi * 8;
    short8 qf[4];
    #pragma unroll
    for (int ks = 0; ks < 4; ks++) {
        const float4 a0 = *(const float4*)(qptr + ks * 16);
        const float4 a1 = *(const float4*)(qptr + ks * 16 + 4);
        const u32x4 u = {pack2(a0.x * kscale, a0.y * kscale), pack2(a0.z * kscale, a0.w * kscale),
                         pack2(a1.x * kscale, a1.y * kscale), pack2(a1.z * kscale, a1.w * kscale)};
        qf[ks] = __builtin_bit_cast(short8, u);
    }

    const size_t bh = (size_t)(b * 8 + h);
    const u16* kcb = kc + bh * 131072;
    const u16* vtb = vt + bh * 131072;

    auto loadK = [&](int kt, int mt, int ks) -> short8 {
        if constexpr (SRC == 0) {
            const u32x4 u = *(const u32x4*)&kcb[(size_t)kt * 4096 + (mt * 4 + ks) * 512 + lane * 8];
            return __builtin_bit_cast(short8, u);
        } else {
            const float* p = kk + (((size_t)b * S_ + kt * 64 + mt * 32 + l31) * H_ + h) * E_ + ks * 16 + hi * 8;
            const float4 a0 = *(const float4*)p;
            const float4 a1 = *(const float4*)(p + 4);
            const u32x4 u = {pack2(a0.x, a0.y), pack2(a0.z, a0.w), pack2(a1.x, a1.y), pack2(a1.z, a1.w)};
            return __builtin_bit_cast(short8, u);
        }
    };
    auto loadV = [&](int kt, int nt, int ks) -> short8 {
        if constexpr (SRC == 0) {
            const u32x4 u = *(const u32x4*)&vtb[(size_t)kt * 4096 + (nt * 4 + ks) * 512 + lane * 8];
            return __builtin_bit_cast(short8, u);
        } else {
            float f[8];
            #pragma unroll
            for (int jj = 0; jj < 8; jj++)
                f[jj] = vv[(((size_t)b * S_ + kt * 64 + ks * 16 + hi * 8 + jj) * H_ + h) * D_ + nt * 32 + l31];
            const u32x4 u = {pack2(f[0], f[1]), pack2(f[2], f[3]), pack2(f[4], f[5]), pack2(f[6], f[7])};
            return __builtin_bit_cast(short8, u);
        }
    };

    floatx16 occ[2] = {zero16(), zero16()};  // O^T: col = q = l31
    float m_run = -1e30f, l_run = 0.f;

    short8 kf[2][4], vf[2][4];
    #pragma unroll
    for (int mt = 0; mt < 2; mt++)
        #pragma unroll
        for (int ks = 0; ks < 4; ks++) { kf[mt][ks] = loadK(kt0, mt, ks); vf[mt][ks] = loadV(kt0, mt, ks); }

    for (int kt = kt0; kt <= ktend; kt++) {
        // ---- S^T = K*Q^T ----
        floatx16 sac[2];
        __builtin_amdgcn_s_setprio(1);
        #pragma unroll
        for (int mt = 0; mt < 2; mt++) {
            floatx16 c = zero16();
            #pragma unroll
            for (int ks = 0; ks < 4; ks++)
                c = __builtin_amdgcn_mfma_f32_32x32x16_bf16(kf[mt][ks], qf[ks], c, 0, 0, 0);
            sac[mt] = c;
        }
        __builtin_amdgcn_s_setprio(0);

        if (kt < ktend) {   // prefetch next K tile
            #pragma unroll
            for (int mt = 0; mt < 2; mt++)
                #pragma unroll
                for (int ks = 0; ks < 4; ks++) kf[mt][ks] = loadK(kt + 1, mt, ks);
        }

        // ---- causal mask (diagonal tile only; wave-uniform) ----
        if (diag && kt == ktend) {
            const int qg = q0 + l31;
            #pragma unroll
            for (int mt = 0; mt < 2; mt++)
                #pragma unroll
                for (int r = 0; r < 16; r++) {
                    const int keyg = kt * 64 + mt * 32 + (r & 3) + (r >> 2) * 8 + hi * 4;
                    if (keyg > qg) sac[mt][r] = -1e30f;
                }
        }

        // ---- online softmax, in-lane + 1 shfl; defer-max (THR=8, log2 dom) ----
        float red[16];
        #pragma unroll
        for (int r = 0; r < 16; r++) red[r] = fmaxf(sac[0][r], sac[1][r]);
        #pragma unroll
        for (int stp = 8; stp > 0; stp >>= 1)
            #pragma unroll
            for (int r = 0; r < stp; r++) red[r] = fmaxf(red[r], red[r + stp]);
        const float mx = fmaxf(red[0], __shfl_xor(red[0], 32));

        const bool defer = __all(mx - m_run <= 8.0f) != 0;
        if (!defer) {
            const float mnew  = fmaxf(m_run, mx);
            const float alpha = exp2f(m_run - mnew);
            m_run = mnew;
            l_run *= alpha;
            #pragma unroll
            for (int nt = 0; nt < 2; nt++)
                #pragma unroll
                for (int r = 0; r < 16; r++) occ[nt][r] *= alpha;
        }

        float sum[16];
        #pragma unroll
        for (int r = 0; r < 16; r++) {
            sac[0][r] = exp2f(sac[0][r] - m_run);
            sac[1][r] = exp2f(sac[1][r] - m_run);
            sum[r] = sac[0][r] + sac[1][r];
        }
        #pragma unroll
        for (int stp = 8; stp > 0; stp >>= 1)
            #pragma unroll
            for (int r = 0; r < stp; r++) sum[r] += sum[r + stp];
        l_run += sum[0] + __shfl_xor(sum[0], 32);

        // ---- P -> bf16 pairs ----
        u32 pk0[8], pk1[8];
        #pragma unroll
        for (int r2 = 0; r2 < 4; r2++) {
            pk0[r2 * 2 + 0] = pack2(sac[0][4 * r2 + 0], sac[0][4 * r2 + 1]);
            pk0[r2 * 2 + 1] = pack2(sac[0][4 * r2 + 2], sac[0][4 * r2 + 3]);
            pk1[r2 * 2 + 0] = pack2(sac[1][4 * r2 + 0], sac[1][4 * r2 + 1]);
            pk1[r2 * 2 + 1] = pack2(sac[1][4 * r2 + 2], sac[1][4 * r2 + 3]);
        }

        // ---- O^T += V^T * P (permlane32_swap builds B-frags) ----
        __builtin_amdgcn_s_setprio(1);
        #pragma unroll
        for (int ks = 0; ks < 4; ks++) {
            const int u = (ks & 1) * 4;
            u32 w0, w1, w2, w3;
            if (ks < 2) { w0 = pk0[u]; w1 = pk0[u + 1]; w2 = pk0[u + 2]; w3 = pk0[u + 3]; }
            else        { w0 = pk1[u]; w1 = pk1[u + 1]; w2 = pk1[u + 2]; w3 = pk1[u + 3]; }
            pl32swap(w0, w2);
            pl32swap(w1, w3);
            const u32x4 pw = {w0, w1, w2, w3};
            const short8 pf = __builtin_bit_cast(short8, pw);
            occ[0] = __builtin_amdgcn_mfma_f32_32x32x16_bf16(vf[0][ks], pf, occ[0], 0, 0, 0);
            occ[1] = __builtin_amdgcn_mfma_f32_32x32x16_bf16(vf[1][ks], pf, occ[1], 0, 0, 0);
        }
        __builtin_amdgcn_s_setprio(0);

        if (kt < ktend) {   // prefetch next V tile
            #pragma unroll
            for (int nt = 0; nt < 2; nt++)
                #pragma unroll
                for (int ks = 0; ks < 4; ks++) vf[nt][ks] = loadV(kt + 1, nt, ks);
        }
    }

    // ---- epilogue ----
    if (split) {
        if (w == 1) {
            #pragma unroll
            for (int nt = 0; nt < 2; nt++)
                #pragma unroll
                for (int r = 0; r < 16; r++) Ls[lane * 33 + nt * 16 + r] = occ[nt][r];
            Ls[2112 + lane] = m_run;
            Ls[2176 + lane] = l_run;
        }
        __syncthreads();
        if (w == 0) {
            const float mB = Ls[2112 + lane], lB = Ls[2176 + lane];
            const float m  = fmaxf(m_run, mB);
            const float aA = exp2f(m_run - m), aB = exp2f(mB - m);
            const float inv = 1.0f / (l_run * aA + lB * aB);
            float* op = out + (((size_t)b * L_ + q0 + l31) * H_ + h) * D_;
            #pragma unroll
            for (int nt = 0; nt < 2; nt++)
                #pragma unroll
                for (int r2 = 0; r2 < 4; r2++) {
                    const float4 o = {
                        (occ[nt][4 * r2 + 0] * aA + Ls[lane * 33 + nt * 16 + 4 * r2 + 0] * aB) * inv,
                        (occ[nt][4 * r2 + 1] * aA + Ls[lane * 33 + nt * 16 + 4 * r2 + 1] * aB) * inv,
                        (occ[nt][4 * r2 + 2] * aA + Ls[lane * 33 + nt * 16 + 4 * r2 + 2] * aB) * inv,
                        (occ[nt][4 * r2 + 3] * aA + Ls[lane * 33 + nt * 16 + 4 * r2 + 3] * aB) * inv};
                    *(float4*)(op + nt * 32 + r2 * 8 + hi * 4) = o;
                }
        }
    } else {
        const float inv = 1.0f / l_run;
        float* op = out + (((size_t)b * L_ + q0 + l31) * H_ + h) * D_;
        #pragma unroll
        for (int nt = 0; nt < 2; nt++)
            #pragma unroll
            for (int r2 = 0; r2 < 4; r2++) {
                const float4 o = {occ[nt][4 * r2 + 0] * inv, occ[nt][4 * r2 + 1] * inv,
                                  occ[nt][4 * r2 + 2] * inv, occ[nt][4 * r2 + 3] * inv};
                *(float4*)(op + nt * 32 + r2 * 8 + hi * 4) = o;
            }
    }
}

extern "C" void kernel_launch(void* const* d_in, const int* in_sizes, int n_in,
                              void* d_out, int out_size, void* d_ws, size_t ws_size,
                              hipStream_t stream) {
    const float* q = (const float*)d_in[0];
    const float* k = (const float*)d_in[1];
    const float* v = (const float*)d_in[2];
    // d_in[3] = attn_mask: fixed causal triu -> handled analytically in-kernel.
    float* out = (float*)d_out;

    const size_t elems = (size_t)B_ * H_ * S_ * E_;   // per tensor (u16 count)
    const size_t need  = elems * 2 * 2;               // Kc + Vt, bf16
    if (d_ws != nullptr && ws_size >= need) {
        u16* kc = (u16*)d_ws;
        u16* vt = kc + elems;
        cvt_kernel<<<dim3(2048), dim3(256), 0, stream>>>(k, v, kc, vt);
        fa_kernel<0><<<dim3(1536), dim3(128), 0, stream>>>(q, k, v, kc, vt, out);
    } else {
        fa_kernel<1><<<dim3(1536), dim3(128), 0, stream>>>(q, k, v, nullptr, nullptr, out);
    }
}